// Round 1
// baseline (570.972 us; speedup 1.0000x reference)
//
#include <hip/hip_runtime.h>
#include <math.h>

#define NQ 12
#define NST 4096
#define NDEPTH 6
#define NLAYER 2
#define NTHREADS 256

// GF(2)-linear LDS address swizzle: folds s5,s6,s7,s8,s9 into bank bits so that
// all three transpose patterns (lane bits -> {0..5}, {0..3,8,9}, {4..7,8,9})
// have rank-5 bank maps => <=2-way conflicts (free).
static __device__ __forceinline__ int swz(int s) {
    return s ^ ((s >> 5) & 7) ^ (((s >> 8) & 1) << 4) ^ (((s >> 9) & 1) << 3);
}

// Composed 12-CNOT ring permutation on the 12-bit basis label.
// qubit q <-> bit (11-q). Sequential: for q=0..11: bit(q+r) ^= bit(q) (updated bits).
static __device__ __forceinline__ int cnot_ring(int s, int r) {
#pragma unroll
    for (int q = 0; q < NQ; ++q) {
        int qt = q + r;
        if (qt >= NQ) qt -= NQ;
        s ^= ((s >> (11 - q)) & 1) << (11 - qt);
    }
    return s;
}

// One 1-qubit gate on register-bit B across the 16 register amps.
template <int B>
static __device__ __forceinline__ void apply1(float2* a, float2 u00, float2 u01,
                                              float2 u10, float2 u11) {
#pragma unroll
    for (int j = 0; j < 16; ++j) {
        if (j & B) continue;
        float2 x0 = a[j];
        float2 x1 = a[j | B];
        float2 n0, n1;
        n0.x = u00.x * x0.x - u00.y * x0.y + u01.x * x1.x - u01.y * x1.y;
        n0.y = u00.x * x0.y + u00.y * x0.x + u01.x * x1.y + u01.y * x1.x;
        n1.x = u10.x * x0.x - u10.y * x0.y + u11.x * x1.x - u11.y * x1.y;
        n1.y = u10.x * x0.y + u10.y * x0.x + u11.x * x1.y + u11.y * x1.x;
        a[j] = n0;
        a[j | B] = n1;
    }
}

// Precompute the 144 Rot(phi,theta,omega) 2x2 complex matrices (batch-independent).
// Rot = RZ(om) RY(th) RZ(phi):
//  u00 =  c*e^{-i(phi+om)/2}, u01 = -s*e^{+i(phi-om)/2}
//  u10 =  s*e^{-i(phi-om)/2}, u11 =  c*e^{+i(phi+om)/2}
__global__ void vqc_gates(const float* __restrict__ th, float* __restrict__ gates) {
    int idx = blockIdx.x * blockDim.x + threadIdx.x;
    if (idx >= NLAYER * NDEPTH * NQ) return;
    const float* w = th + idx * 3;
    float phi = w[0], tht = w[1], om = w[2];
    float st, ct, spo, cpo, smo, cmo;
    sincosf(0.5f * tht, &st, &ct);
    sincosf(0.5f * (phi + om), &spo, &cpo);
    sincosf(0.5f * (phi - om), &smo, &cmo);
    float* o = gates + idx * 8;
    o[0] = ct * cpo;  o[1] = -ct * spo;   // u00
    o[2] = -st * cmo; o[3] = -st * smo;   // u01
    o[4] = st * cmo;  o[5] = -st * smo;   // u10
    o[6] = ct * cpo;  o[7] = ct * spo;    // u11
}

__global__ __launch_bounds__(NTHREADS, 4) void vqc_main(
        const float* __restrict__ x,
        const float* __restrict__ gates,
        float* __restrict__ out) {
    __shared__ float lre[NST];
    __shared__ float lim[NST];

    const int b = blockIdx.x;
    const int t = threadIdx.x;
    const int lane = t & 63;
    const int wv = t >> 6;

    float2 a[16];  // register-resident amps; assignment A: s = (j<<8) | t

    for (int l = 0; l < NLAYER; ++l) {
        // ---- per-qubit angles: lane q computes sincos, broadcast via shfl ----
        float myang = 0.0f;
        if (l == 0) {
            if (lane < NQ) myang = x[b * NQ + lane];
        } else {
            if (lane < NQ) myang = lre[64 + lane];  // expvals from previous layer
        }
        float sv, cv;
        sincosf(0.5f * myang, &sv, &cv);
        float cq[NQ], sq[NQ];
#pragma unroll
        for (int q = 0; q < NQ; ++q) {
            cq[q] = __shfl(cv, q, 64);
            sq[q] = __shfl(sv, q, 64);
        }
        __syncthreads();  // scratch reads done; LDS free for transposes

        // ---- init product state |psi> = prod RY(ang_q)|0> (real) ----
        // s bit j (j<8) = t bit j -> qubit 11-j; reg-bit jb -> qubit 3-jb
        float pl = 1.0f;
#pragma unroll
        for (int jb = 0; jb < 8; ++jb)
            pl *= ((t >> jb) & 1) ? sq[11 - jb] : cq[11 - jb];
#pragma unroll
        for (int j = 0; j < 16; ++j) {
            float f = pl;
#pragma unroll
            for (int jb = 0; jb < 4; ++jb)
                f *= ((j >> jb) & 1) ? sq[3 - jb] : cq[3 - jb];
            a[j] = make_float2(f, 0.0f);
        }

        const float2* gl = (const float2*)gates + (size_t)(l * NDEPTH) * NQ * 4;
        for (int d = 0; d < NDEPTH; ++d) {
            const float2* gd = gl + d * NQ * 4;

            // phase A: qubits 0..3 on reg bits 3..0
            apply1<8>(a, gd[0], gd[1], gd[2], gd[3]);
            apply1<4>(a, gd[4], gd[5], gd[6], gd[7]);
            apply1<2>(a, gd[8], gd[9], gd[10], gd[11]);
            apply1<1>(a, gd[12], gd[13], gd[14], gd[15]);

            // transpose A -> B   (B: s = (t&15) | (j<<4) | ((t>>4)<<8))
            {
                int base = swz(t);
#pragma unroll
                for (int j = 0; j < 16; ++j) {
                    int addr = base ^ swz(j << 8);
                    lre[addr] = a[j].x;
                    lim[addr] = a[j].y;
                }
            }
            __syncthreads();
            {
                int base = swz((t & 15) | ((t >> 4) << 8));
#pragma unroll
                for (int j = 0; j < 16; ++j) {
                    int addr = base ^ swz(j << 4);
                    a[j].x = lre[addr];
                    a[j].y = lim[addr];
                }
            }
            __syncthreads();

            // phase B: qubits 4..7
            apply1<8>(a, gd[16], gd[17], gd[18], gd[19]);
            apply1<4>(a, gd[20], gd[21], gd[22], gd[23]);
            apply1<2>(a, gd[24], gd[25], gd[26], gd[27]);
            apply1<1>(a, gd[28], gd[29], gd[30], gd[31]);

            // transpose B -> C   (C: s = j | ((t&15)<<4) | ((t>>4)<<8))
            {
                int base = swz((t & 15) | ((t >> 4) << 8));
#pragma unroll
                for (int j = 0; j < 16; ++j) {
                    int addr = base ^ swz(j << 4);
                    lre[addr] = a[j].x;
                    lim[addr] = a[j].y;
                }
            }
            __syncthreads();
            {
                int base = swz(((t & 15) << 4) | ((t >> 4) << 8));
#pragma unroll
                for (int j = 0; j < 16; ++j) {
                    int addr = base ^ j;  // swz(j)==j for j<16
                    a[j].x = lre[addr];
                    a[j].y = lim[addr];
                }
            }
            __syncthreads();

            // phase C: qubits 8..11
            apply1<8>(a, gd[32], gd[33], gd[34], gd[35]);
            apply1<4>(a, gd[36], gd[37], gd[38], gd[39]);
            apply1<2>(a, gd[40], gd[41], gd[42], gd[43]);
            apply1<1>(a, gd[44], gd[45], gd[46], gd[47]);

            // transpose C -> A, CNOT ring folded into the scattered write:
            // new[f(s)] = old[s], f linear => addr = swz(f(base)) ^ swz(f(j-bit)) consts
            {
                int r = d + 1;
                int sf1 = swz(cnot_ring(1, r));
                int sf2 = swz(cnot_ring(2, r));
                int sf4 = swz(cnot_ring(4, r));
                int sf8 = swz(cnot_ring(8, r));
                int sC = ((t & 15) << 4) | ((t >> 4) << 8);
                int base = swz(cnot_ring(sC, r));
#pragma unroll
                for (int j = 0; j < 16; ++j) {
                    int addr = base;
                    if (j & 1) addr ^= sf1;
                    if (j & 2) addr ^= sf2;
                    if (j & 4) addr ^= sf4;
                    if (j & 8) addr ^= sf8;
                    lre[addr] = a[j].x;
                    lim[addr] = a[j].y;
                }
            }
            __syncthreads();
            {
                int base = swz(t);
#pragma unroll
                for (int j = 0; j < 16; ++j) {
                    int addr = base ^ swz(j << 8);
                    a[j].x = lre[addr];
                    a[j].y = lim[addr];
                }
            }
            __syncthreads();
        }

        // ---- readout: <Z_q> = sum p(s) * (1 - 2*bit_q(s)) ----
        float T = 0.f, e0 = 0.f, e1 = 0.f, e2 = 0.f, e3 = 0.f;
#pragma unroll
        for (int j = 0; j < 16; ++j) {
            float p = a[j].x * a[j].x + a[j].y * a[j].y;
            T += p;
            e3 += (j & 1) ? -p : p;   // qubit 3 <-> s bit 8 <-> j bit 0
            e2 += (j & 2) ? -p : p;
            e1 += (j & 4) ? -p : p;
            e0 += (j & 8) ? -p : p;
        }
        float e[NQ];
        e[0] = e0; e[1] = e1; e[2] = e2; e[3] = e3;
#pragma unroll
        for (int q = 4; q < NQ; ++q)
            e[q] = ((t >> (11 - q)) & 1) ? -T : T;  // qubit q <-> t bit (11-q)
#pragma unroll
        for (int q = 0; q < NQ; ++q) {
            float v = e[q];
            v += __shfl_down(v, 32, 64);
            v += __shfl_down(v, 16, 64);
            v += __shfl_down(v, 8, 64);
            v += __shfl_down(v, 4, 64);
            v += __shfl_down(v, 2, 64);
            v += __shfl_down(v, 1, 64);
            e[q] = v;
        }
        if (lane == 0) {
#pragma unroll
            for (int q = 0; q < NQ; ++q) lre[wv * NQ + q] = e[q];
        }
        __syncthreads();
        if (l == 0) {
            if (t < NQ) {
                float s = lre[t] + lre[NQ + t] + lre[2 * NQ + t] + lre[3 * NQ + t];
                lre[64 + t] = s;  // angles for next layer
            }
            __syncthreads();
        } else {
            if (t >= 3 && t < 9) {
                float s = lre[t] + lre[NQ + t] + lre[2 * NQ + t] + lre[3 * NQ + t];
                out[b * 6 + (t - 3)] = s * 3.14159253438047729f;  // pi - f32 eps
            }
        }
    }
}

extern "C" void kernel_launch(void* const* d_in, const int* in_sizes, int n_in,
                              void* d_out, int out_size, void* d_ws, size_t ws_size,
                              hipStream_t stream) {
    const float* x = (const float*)d_in[0];
    const float* th = (const float*)d_in[1];
    float* outp = (float*)d_out;
    float* gates = (float*)d_ws;  // 144 * 8 floats = 4608 B

    int batch = in_sizes[0] / NQ;

    hipLaunchKernelGGL(vqc_gates, dim3(1), dim3(192), 0, stream, th, gates);
    hipLaunchKernelGGL(vqc_main, dim3(batch), dim3(NTHREADS), 0, stream, x, gates, outp);
}